// Round 1
// baseline (233.697 us; speedup 1.0000x reference)
//
#include <hip/hip_runtime.h>
#include <hip/hip_bf16.h>

// Problem constants
#define BB 4096
#define GG 8
#define CIN 512
#define CH 1024
#define COUT 64

// ---------------------------------------------------------------------------
// Kernel 1: bucket samples by expert id. Single block, LDS histogram + scan.
// Writes offs[9] (group start offsets, offs[8]=B) and perm[B] (sample ids
// grouped by expert; order within group is arbitrary — results don't depend
// on it since each row is computed independently).
// ---------------------------------------------------------------------------
__global__ __launch_bounds__(1024) void bucket_kernel(
    const int* __restrict__ gid, int B, int* __restrict__ offs,
    int* __restrict__ perm) {
  __shared__ int cnt[GG];
  __shared__ int cur[GG];
  int tid = threadIdx.x;
  if (tid < GG) cnt[tid] = 0;
  __syncthreads();
  for (int b = tid; b < B; b += blockDim.x) atomicAdd(&cnt[gid[b]], 1);
  __syncthreads();
  if (tid == 0) {
    int o = 0;
    for (int g = 0; g < GG; g++) {
      offs[g] = o;
      cur[g] = o;
      o += cnt[g];
    }
    offs[GG] = o;
  }
  __syncthreads();
  for (int b = tid; b < B; b += blockDim.x) {
    int pos = atomicAdd(&cur[gid[b]], 1);
    perm[pos] = b;
  }
}

// ---------------------------------------------------------------------------
// Grouped tiled SGEMM: C[rows, n0:n0+64] = act(A[rows,:K] * Bm[g] + bias[g])
//   A: row-major, ld = K (gathered rows via perm)
//   Bm: [G, K, N] row-major
//   C: row-major, ld = N (scattered rows via perm)
// Block: 256 threads, 64x64 tile, BK=16, 4x4 register tile per thread.
// blockIdx.y = g * maxTiles + t  (early-exit if tile beyond group's count)
// ---------------------------------------------------------------------------
template <int K, int N, bool RELU>
__global__ __launch_bounds__(256) void grouped_gemm_kernel(
    const float* __restrict__ A, const float* __restrict__ Bm,
    const float* __restrict__ bias, const int* __restrict__ offs,
    const int* __restrict__ perm, float* __restrict__ C, int maxTiles) {
  const int BM = 64, BN = 64, BK = 16;
  int g = blockIdx.y / maxTiles;
  int t = blockIdx.y % maxTiles;
  int start = offs[g];
  int cnt = offs[g + 1] - start;
  int row0 = t * BM;
  if (row0 >= cnt) return;
  int n0 = blockIdx.x * BN;

  __shared__ float As[BK][BM];
  __shared__ float Bs[BK][BN];
  __shared__ int rows[BM];

  int tid = threadIdx.x;
  if (tid < BM) {
    int r = row0 + tid;
    rows[tid] = (r < cnt) ? perm[start + r] : -1;
  }
  __syncthreads();

  // register tile coords
  int tm = (tid >> 4) << 2;  // 0,4,...,60
  int tn = (tid & 15) << 2;  // 0,4,...,60
  float acc[4][4] = {};

  // staging-load coords
  int la_r = tid >> 2;         // 0..63
  int la_k = (tid & 3) << 2;   // 0,4,8,12
  int lb_k = tid >> 4;         // 0..15
  int lb_n = (tid & 15) << 2;  // 0..60

  const float* Bg = Bm + (size_t)g * K * N;
  int arow = rows[la_r];
  const float* aptr = (arow >= 0) ? (A + (size_t)arow * K + la_k) : nullptr;

  for (int k0 = 0; k0 < K; k0 += BK) {
    float4 av = make_float4(0.f, 0.f, 0.f, 0.f);
    if (aptr) av = *(const float4*)(aptr + k0);
    As[la_k + 0][la_r] = av.x;
    As[la_k + 1][la_r] = av.y;
    As[la_k + 2][la_r] = av.z;
    As[la_k + 3][la_r] = av.w;
    float4 bv = *(const float4*)(Bg + (size_t)(k0 + lb_k) * N + n0 + lb_n);
    *(float4*)&Bs[lb_k][lb_n] = bv;
    __syncthreads();
#pragma unroll
    for (int kk = 0; kk < BK; kk++) {
      float a[4], b[4];
      *(float4*)a = *(const float4*)&As[kk][tm];
      *(float4*)b = *(const float4*)&Bs[kk][tn];
#pragma unroll
      for (int i = 0; i < 4; i++)
#pragma unroll
        for (int j = 0; j < 4; j++) acc[i][j] += a[i] * b[j];
    }
    __syncthreads();
  }

  float bb[4];
  *(float4*)bb = *(const float4*)(bias + (size_t)g * N + n0 + tn);
#pragma unroll
  for (int i = 0; i < 4; i++) {
    int r = rows[tm + i];
    if (r < 0) continue;
    float4 o;
    o.x = acc[i][0] + bb[0];
    o.y = acc[i][1] + bb[1];
    o.z = acc[i][2] + bb[2];
    o.w = acc[i][3] + bb[3];
    if (RELU) {
      o.x = fmaxf(o.x, 0.f);
      o.y = fmaxf(o.y, 0.f);
      o.z = fmaxf(o.z, 0.f);
      o.w = fmaxf(o.w, 0.f);
    }
    *(float4*)(C + (size_t)r * N + n0 + tn) = o;
  }
}

extern "C" void kernel_launch(void* const* d_in, const int* in_sizes, int n_in,
                              void* d_out, int out_size, void* d_ws,
                              size_t ws_size, hipStream_t stream) {
  const float* x = (const float*)d_in[0];
  const int* gid = (const int*)d_in[1];
  const float* W1 = (const float*)d_in[2];
  const float* b1 = (const float*)d_in[3];
  const float* W2 = (const float*)d_in[4];
  const float* b2 = (const float*)d_in[5];
  float* y = (float*)d_out;

  const int B = in_sizes[1];  // 4096

  // workspace layout
  int* offs = (int*)d_ws;           // 9 ints
  int* perm = offs + 16;            // B ints (offset 64 bytes)
  float* h = (float*)((char*)d_ws + 64 + (size_t)B * sizeof(int));  // [B, CH]

  bucket_kernel<<<1, 1024, 0, stream>>>(gid, B, offs, perm);

  int maxTiles = (B + 63) / 64;  // 64
  dim3 grid1(CH / 64, GG * maxTiles);
  grouped_gemm_kernel<CIN, CH, true><<<grid1, 256, 0, stream>>>(
      x, W1, b1, offs, perm, h, maxTiles);

  dim3 grid2(COUT / 64, GG * maxTiles);
  grouped_gemm_kernel<CH, COUT, false><<<grid2, 256, 0, stream>>>(
      h, W2, b2, offs, perm, y, maxTiles);
}

// Round 2
// 216.314 us; speedup vs baseline: 1.0804x; 1.0804x over previous
//
#include <hip/hip_runtime.h>
#include <hip/hip_bf16.h>

#define B_ 4096
#define G_ 8
#define IN_ 512
#define H_ 1024
#define OUT_ 64

typedef float f32x4 __attribute__((ext_vector_type(4)));
typedef __bf16 bf16x8 __attribute__((ext_vector_type(8)));
typedef unsigned short u16x8 __attribute__((ext_vector_type(8)));

// f32 -> bf16 round-to-nearest-even
__device__ inline unsigned short f2bf(float f) {
  unsigned int u = __builtin_bit_cast(unsigned int, f);
  u += 0x7fffu + ((u >> 16) & 1u);
  return (unsigned short)(u >> 16);
}

// async global->LDS, 16B per lane. LDS dest is wave-uniform base + lane*16.
__device__ inline void gl_lds16(const void* g, void* l) {
  __builtin_amdgcn_global_load_lds(
      (const __attribute__((address_space(1))) unsigned int*)g,
      (__attribute__((address_space(3))) unsigned int*)l, 16, 0, 0);
}

// ---------------------------------------------------------------------------
// bucket: offs[9] group offsets, perm[B] sample ids grouped by expert
// ---------------------------------------------------------------------------
__global__ __launch_bounds__(1024) void bucket_kernel(
    const int* __restrict__ gid, int* __restrict__ offs,
    int* __restrict__ perm) {
  __shared__ int cnt[G_];
  __shared__ int cur[G_];
  int tid = threadIdx.x;
  if (tid < G_) cnt[tid] = 0;
  __syncthreads();
  for (int b = tid; b < B_; b += blockDim.x) atomicAdd(&cnt[gid[b]], 1);
  __syncthreads();
  if (tid == 0) {
    int o = 0;
    for (int g = 0; g < G_; g++) {
      offs[g] = o;
      cur[g] = o;
      o += cnt[g];
    }
    offs[G_] = o;
  }
  __syncthreads();
  for (int b = tid; b < B_; b += blockDim.x) {
    int pos = atomicAdd(&cur[gid[b]], 1);
    perm[pos] = b;
  }
}

// ---------------------------------------------------------------------------
// W1 [G][IN][H] f32  ->  W1t [G][H][IN] bf16   (32x32 LDS tile transpose)
// grid (H/32, IN/32, G), 256 threads
// ---------------------------------------------------------------------------
__global__ __launch_bounds__(256) void transpose_w1_kernel(
    const float* __restrict__ W1, unsigned short* __restrict__ W1t) {
  __shared__ float tile[32][33];
  int g = blockIdx.z, kt = blockIdx.y, nt = blockIdx.x;
  int t = threadIdx.x;
  int kl = t >> 3, nl = (t & 7) * 4;
  const float* src =
      W1 + ((size_t)g * IN_ + kt * 32 + kl) * H_ + nt * 32 + nl;
  float4 v = *(const float4*)src;
  tile[kl][nl + 0] = v.x;
  tile[kl][nl + 1] = v.y;
  tile[kl][nl + 2] = v.z;
  tile[kl][nl + 3] = v.w;
  __syncthreads();
  int nl2 = t >> 3, kl2 = (t & 7) * 4;
  ushort4 o;
  o.x = f2bf(tile[kl2 + 0][nl2]);
  o.y = f2bf(tile[kl2 + 1][nl2]);
  o.z = f2bf(tile[kl2 + 2][nl2]);
  o.w = f2bf(tile[kl2 + 3][nl2]);
  *(ushort4*)(W1t + ((size_t)g * H_ + nt * 32 + nl2) * IN_ + kt * 32 + kl2) =
      o;
}

// ---------------------------------------------------------------------------
// gemm1: hb[start+local][0:H] = relu(x[perm]·W1t[g] + b1[g])  (bf16 out,
// permuted-contiguous rows). BM=128 BN=64 BK=32, 4 waves, wave tile 64x32,
// mfma_f32_16x16x32_bf16. LDS chunk-XOR swizzle: element chunk c of row r
// lives at slot c ^ ((r>>1)&3) -> all b128 frag reads are 2-way (free).
// 1D grid: f = ntile*256 + (g*32 + rowtile); same-A blocks share XCD.
// ---------------------------------------------------------------------------
__global__ __launch_bounds__(256) void gemm1_kernel(
    const float* __restrict__ x, const unsigned short* __restrict__ W1t,
    const float* __restrict__ b1, const int* __restrict__ offs,
    const int* __restrict__ perm, unsigned short* __restrict__ hb) {
  int f = blockIdx.x;
  int yb = f & 255;
  int g = yb >> 5;
  int tb = yb & 31;
  int start = offs[g];
  int cnt = offs[g + 1] - start;
  int row0 = tb * 128;
  if (row0 >= cnt) return;
  int n0 = (f >> 8) * 64;

  __shared__ __attribute__((aligned(16))) unsigned short As[128 * 32];
  __shared__ __attribute__((aligned(16))) unsigned short Bs[64 * 32];
  __shared__ int rows[128];

  int tid = threadIdx.x;
  int lane = tid & 63;
  int wv = tid >> 6;

  if (tid < 128) rows[tid] = perm[start + min(row0 + tid, cnt - 1)];
  __syncthreads();

  // A staging: 2 threads per row, 16 f32 each -> 2 swizzled b128 LDS writes
  int sa_row = tid >> 1;
  int sa_b = tid & 1;
  int s_a = (sa_row >> 1) & 3;
  int c0 = (2 * sa_b) ^ s_a;
  int c1 = c0 ^ 1;
  unsigned short* adst0 = &As[sa_row * 32 + (c0 << 3)];
  unsigned short* adst1 = &As[sa_row * 32 + (c1 << 3)];
  const float* xsrc = x + (size_t)rows[sa_row] * IN_ + sa_b * 16;

  // B staging: global_load_lds, wave wv covers Bs rows wv*16..+15; the
  // per-lane SOURCE chunk is XOR-permuted so LDS slot c holds chunk c^s(row).
  int sb_row = wv * 16 + (lane >> 2);
  int sb_chunk = (lane & 3) ^ ((sb_row >> 1) & 3);
  const unsigned short* bsrc =
      W1t + ((size_t)g * H_ + n0 + sb_row) * IN_ + (sb_chunk << 3);
  unsigned short* bdst = &Bs[wv * 512];

  // fragment offsets (swizzled reads: slot q^s(row))
  int fl = lane & 15;
  int q = lane >> 4;
  int ko = ((q ^ ((lane >> 1) & 3)) << 3);
  int m_half = (wv >> 1) * 64;
  int n_half = (wv & 1) * 32;
  const unsigned short* afrag = &As[(m_half + fl) * 32 + ko];
  const unsigned short* bfrag = &Bs[(n_half + fl) * 32 + ko];

  f32x4 acc[4][2];
#pragma unroll
  for (int i = 0; i < 4; i++)
#pragma unroll
    for (int j = 0; j < 2; j++) acc[i][j] = f32x4{0.f, 0.f, 0.f, 0.f};

  for (int k0 = 0; k0 < IN_; k0 += 32) {
    float4 v0 = *(const float4*)(xsrc + k0);
    float4 v1 = *(const float4*)(xsrc + k0 + 4);
    float4 v2 = *(const float4*)(xsrc + k0 + 8);
    float4 v3 = *(const float4*)(xsrc + k0 + 12);
    u16x8 p0 = {f2bf(v0.x), f2bf(v0.y), f2bf(v0.z), f2bf(v0.w),
                f2bf(v1.x), f2bf(v1.y), f2bf(v1.z), f2bf(v1.w)};
    u16x8 p1 = {f2bf(v2.x), f2bf(v2.y), f2bf(v2.z), f2bf(v2.w),
                f2bf(v3.x), f2bf(v3.y), f2bf(v3.z), f2bf(v3.w)};
    __syncthreads();  // previous iter's consumers done
    gl_lds16(bsrc + k0, bdst);
    *(u16x8*)adst0 = p0;
    *(u16x8*)adst1 = p1;
    __syncthreads();  // staging visible (drains vmcnt+lgkm)
    bf16x8 a0 = *(const bf16x8*)(afrag + 0 * 16 * 32);
    bf16x8 a1 = *(const bf16x8*)(afrag + 1 * 16 * 32);
    bf16x8 a2 = *(const bf16x8*)(afrag + 2 * 16 * 32);
    bf16x8 a3 = *(const bf16x8*)(afrag + 3 * 16 * 32);
    bf16x8 fb0 = *(const bf16x8*)(bfrag + 0 * 16 * 32);
    bf16x8 fb1 = *(const bf16x8*)(bfrag + 1 * 16 * 32);
    acc[0][0] = __builtin_amdgcn_mfma_f32_16x16x32_bf16(a0, fb0, acc[0][0], 0, 0, 0);
    acc[1][0] = __builtin_amdgcn_mfma_f32_16x16x32_bf16(a1, fb0, acc[1][0], 0, 0, 0);
    acc[2][0] = __builtin_amdgcn_mfma_f32_16x16x32_bf16(a2, fb0, acc[2][0], 0, 0, 0);
    acc[3][0] = __builtin_amdgcn_mfma_f32_16x16x32_bf16(a3, fb0, acc[3][0], 0, 0, 0);
    acc[0][1] = __builtin_amdgcn_mfma_f32_16x16x32_bf16(a0, fb1, acc[0][1], 0, 0, 0);
    acc[1][1] = __builtin_amdgcn_mfma_f32_16x16x32_bf16(a1, fb1, acc[1][1], 0, 0, 0);
    acc[2][1] = __builtin_amdgcn_mfma_f32_16x16x32_bf16(a2, fb1, acc[2][1], 0, 0, 0);
    acc[3][1] = __builtin_amdgcn_mfma_f32_16x16x32_bf16(a3, fb1, acc[3][1], 0, 0, 0);
    __syncthreads();  // consumers done before next overwrite
  }

  // epilogue: bias + relu + bf16 store, permuted-contiguous rows
#pragma unroll
  for (int nt = 0; nt < 2; nt++) {
    int col = n0 + n_half + nt * 16 + fl;
    float bias = b1[g * H_ + col];
#pragma unroll
    for (int mt = 0; mt < 4; mt++) {
#pragma unroll
      for (int r = 0; r < 4; r++) {
        int rl = m_half + mt * 16 + q * 4 + r;
        if (row0 + rl < cnt) {
          float v = fmaxf(acc[mt][nt][r] + bias, 0.f);
          hb[(size_t)(start + row0 + rl) * H_ + col] = f2bf(v);
        }
      }
    }
  }
}

// ---------------------------------------------------------------------------
// gemm2: y[perm[row]] += hb[row]·W2[g] (+b2 on kc==0). K split 4x256.
// A via global_load_lds (2 per wave), W2 transposed+cvt in VGPR staging.
// grid (4, 256): x=kc, y=g*32+rowtile
// ---------------------------------------------------------------------------
__global__ __launch_bounds__(256) void gemm2_kernel(
    const unsigned short* __restrict__ hb, const float* __restrict__ W2,
    const float* __restrict__ b2, const int* __restrict__ offs,
    const int* __restrict__ perm, float* __restrict__ y) {
  int kc = blockIdx.x;
  int g = blockIdx.y >> 5;
  int tb = blockIdx.y & 31;
  int start = offs[g];
  int cnt = offs[g + 1] - start;
  int row0 = tb * 128;
  if (row0 >= cnt) return;

  __shared__ __attribute__((aligned(16))) unsigned short As[128 * 32];
  __shared__ __attribute__((aligned(16))) unsigned short Bs[64 * 32];
  __shared__ int rows[128];

  int tid = threadIdx.x;
  int lane = tid & 63;
  int wv = tid >> 6;
  if (tid < 128) rows[tid] = perm[start + min(row0 + tid, cnt - 1)];

  // A staging: wave wv covers rows wv*32..+31 (two 1KB gl_lds ops)
  int sa_slot = lane & 3;
  int r0a = wv * 32 + (lane >> 2);
  int r1a = r0a + 16;
  const unsigned short* asrc0 =
      hb + (size_t)(start + min(row0 + r0a, cnt - 1)) * H_ + kc * 256 +
      (((sa_slot ^ ((r0a >> 1) & 3))) << 3);
  const unsigned short* asrc1 =
      hb + (size_t)(start + min(row0 + r1a, cnt - 1)) * H_ + kc * 256 +
      (((sa_slot ^ ((r1a >> 1) & 3))) << 3);
  unsigned short* adst0 = &As[wv * 1024];
  unsigned short* adst1 = &As[wv * 1024 + 512];

  // B staging: thread t reads 8 f32 of W2 row k, scatters bf16 to Bs[n][k]
  int sbk = tid >> 3;       // k within tile 0..31
  int sbn = (tid & 7) * 8;  // n base
  const float* bsrc = W2 + ((size_t)g * H_ + kc * 256 + sbk) * OUT_ + sbn;
  int bc = sbk >> 3;   // chunk of k
  int bkw = sbk & 7;   // k within chunk

  int fl = lane & 15;
  int q = lane >> 4;
  int ko = ((q ^ ((lane >> 1) & 3)) << 3);
  int m_half = (wv >> 1) * 64;
  int n_half = (wv & 1) * 32;
  const unsigned short* afrag = &As[(m_half + fl) * 32 + ko];
  const unsigned short* bfrag = &Bs[(n_half + fl) * 32 + ko];

  f32x4 acc[4][2];
#pragma unroll
  for (int i = 0; i < 4; i++)
#pragma unroll
    for (int j = 0; j < 2; j++) acc[i][j] = f32x4{0.f, 0.f, 0.f, 0.f};

  for (int it = 0; it < 8; it++) {
    int k0 = it * 32;
    float4 w0 = *(const float4*)(bsrc + (size_t)k0 * OUT_);
    float4 w1 = *(const float4*)(bsrc + (size_t)k0 * OUT_ + 4);
    unsigned short bv[8] = {f2bf(w0.x), f2bf(w0.y), f2bf(w0.z), f2bf(w0.w),
                            f2bf(w1.x), f2bf(w1.y), f2bf(w1.z), f2bf(w1.w)};
    __syncthreads();
    gl_lds16(asrc0 + k0, adst0);
    gl_lds16(asrc1 + k0, adst1);
#pragma unroll
    for (int j = 0; j < 8; j++) {
      int n = sbn + j;
      Bs[n * 32 + ((bc ^ ((n >> 1) & 3)) << 3) + bkw] = bv[j];
    }
    __syncthreads();
    bf16x8 a0 = *(const bf16x8*)(afrag + 0 * 16 * 32);
    bf16x8 a1 = *(const bf16x8*)(afrag + 1 * 16 * 32);
    bf16x8 a2 = *(const bf16x8*)(afrag + 2 * 16 * 32);
    bf16x8 a3 = *(const bf16x8*)(afrag + 3 * 16 * 32);
    bf16x8 fb0 = *(const bf16x8*)(bfrag + 0 * 16 * 32);
    bf16x8 fb1 = *(const bf16x8*)(bfrag + 1 * 16 * 32);
    acc[0][0] = __builtin_amdgcn_mfma_f32_16x16x32_bf16(a0, fb0, acc[0][0], 0, 0, 0);
    acc[1][0] = __builtin_amdgcn_mfma_f32_16x16x32_bf16(a1, fb0, acc[1][0], 0, 0, 0);
    acc[2][0] = __builtin_amdgcn_mfma_f32_16x16x32_bf16(a2, fb0, acc[2][0], 0, 0, 0);
    acc[3][0] = __builtin_amdgcn_mfma_f32_16x16x32_bf16(a3, fb0, acc[3][0], 0, 0, 0);
    acc[0][1] = __builtin_amdgcn_mfma_f32_16x16x32_bf16(a0, fb1, acc[0][1], 0, 0, 0);
    acc[1][1] = __builtin_amdgcn_mfma_f32_16x16x32_bf16(a1, fb1, acc[1][1], 0, 0, 0);
    acc[2][1] = __builtin_amdgcn_mfma_f32_16x16x32_bf16(a2, fb1, acc[2][1], 0, 0, 0);
    acc[3][1] = __builtin_amdgcn_mfma_f32_16x16x32_bf16(a3, fb1, acc[3][1], 0, 0, 0);
    __syncthreads();
  }

#pragma unroll
  for (int nt = 0; nt < 2; nt++) {
    int col = n_half + nt * 16 + fl;
    float bias = (kc == 0) ? b2[g * OUT_ + col] : 0.f;
#pragma unroll
    for (int mt = 0; mt < 4; mt++) {
#pragma unroll
      for (int r = 0; r < 4; r++) {
        int rl = m_half + mt * 16 + q * 4 + r;
        if (row0 + rl < cnt) {
          unsafeAtomicAdd(&y[(size_t)rows[rl] * OUT_ + col],
                          acc[mt][nt][r] + bias);
        }
      }
    }
  }
}

extern "C" void kernel_launch(void* const* d_in, const int* in_sizes, int n_in,
                              void* d_out, int out_size, void* d_ws,
                              size_t ws_size, hipStream_t stream) {
  const float* x = (const float*)d_in[0];
  const int* gid = (const int*)d_in[1];
  const float* W1 = (const float*)d_in[2];
  const float* b1 = (const float*)d_in[3];
  const float* W2 = (const float*)d_in[4];
  const float* b2 = (const float*)d_in[5];
  float* y = (float*)d_out;

  // ws layout (total 16,793,664 B == round-1 proven footprint)
  int* offs = (int*)d_ws;                                       // @0
  int* perm = (int*)((char*)d_ws + 64);                         // @64
  unsigned short* W1t = (unsigned short*)((char*)d_ws + 16448); // 8 MB
  unsigned short* hb = (unsigned short*)((char*)d_ws + 8405056);// 8 MB

  bucket_kernel<<<1, 1024, 0, stream>>>(gid, offs, perm);
  transpose_w1_kernel<<<dim3(H_ / 32, IN_ / 32, G_), 256, 0, stream>>>(W1, W1t);
  hipMemsetAsync(d_out, 0, (size_t)out_size * sizeof(float), stream);
  gemm1_kernel<<<(H_ / 64) * 256, 256, 0, stream>>>(x, W1t, b1, offs, perm, hb);
  gemm2_kernel<<<dim3(4, 256), 256, 0, stream>>>(hb, W2, b2, offs, perm, y);
}

// Round 5
// 128.524 us; speedup vs baseline: 1.8183x; 1.6831x over previous
//
#include <hip/hip_runtime.h>
#include <hip/hip_bf16.h>

#define B_ 4096
#define G_ 8
#define IN_ 512
#define H_ 1024
#define OUT_ 64
#define MAXT 72  // max 64-row tiles across groups: 64 + 8

typedef float f32x4 __attribute__((ext_vector_type(4)));
typedef __bf16 bf16x8 __attribute__((ext_vector_type(8)));
typedef unsigned short u16x8 __attribute__((ext_vector_type(8)));

__device__ inline unsigned short f2bf(float f) {
  unsigned int u = __builtin_bit_cast(unsigned int, f);
  u += 0x7fffu + ((u >> 16) & 1u);
  return (unsigned short)(u >> 16);
}

__device__ inline u16x8 pack8(float4 a, float4 b) {
  return u16x8{f2bf(a.x), f2bf(a.y), f2bf(a.z), f2bf(a.w),
               f2bf(b.x), f2bf(b.y), f2bf(b.z), f2bf(b.w)};
}

// Tile-table scan: given meta (offs[0..8]) and linear tile id mt, find the
// group g, row0, start, cnt. Returns false if mt >= total tiles.
__device__ inline bool tile_lookup(const int* __restrict__ meta, int mt,
                                   int& g, int& row0, int& start, int& cnt) {
  int ts = 0;
  bool found = false;
#pragma unroll
  for (int gg = 0; gg < G_; gg++) {
    int s = meta[gg], e = meta[gg + 1];
    int T = (e - s + 63) >> 6;
    if (!found && mt >= ts && mt < ts + T) {
      g = gg;
      row0 = (mt - ts) << 6;
      start = s;
      cnt = e - s;
      found = true;
    }
    ts += T;
  }
  return found;
}

// ---------------------------------------------------------------------------
// transpose: W1 [G][IN][H] f32 -> W1t [G][H][IN] bf16 (round-2-proven path)
// grid 4096, 256 threads
// ---------------------------------------------------------------------------
__global__ __launch_bounds__(256) void transpose_w1_kernel(
    const float* __restrict__ W1, unsigned short* __restrict__ W1t) {
  __shared__ float tile[32][33];
  int b = blockIdx.x;
  int h32 = b & 31, k32 = (b >> 5) & 15, g = b >> 9;
  int t = threadIdx.x;
  int kl = t >> 3, nl = (t & 7) * 4;
  const float* src =
      W1 + ((size_t)g * IN_ + k32 * 32 + kl) * H_ + h32 * 32 + nl;
  float4 v = *(const float4*)src;
  tile[kl][nl + 0] = v.x;
  tile[kl][nl + 1] = v.y;
  tile[kl][nl + 2] = v.z;
  tile[kl][nl + 3] = v.w;
  __syncthreads();
  int nl2 = t >> 3, kl2 = (t & 7) * 4;
  ushort4 o;
  o.x = f2bf(tile[kl2 + 0][nl2]);
  o.y = f2bf(tile[kl2 + 1][nl2]);
  o.z = f2bf(tile[kl2 + 2][nl2]);
  o.w = f2bf(tile[kl2 + 3][nl2]);
  *(ushort4*)(W1t + ((size_t)g * H_ + h32 * 32 + nl2) * IN_ + k32 * 32 +
              kl2) = o;
}

// ---------------------------------------------------------------------------
// bucket: DETERMINISTIC stable counting sort. Single block, 256 threads,
// 16 samples/thread. No atomics anywhere -> perm is bit-identical across
// launches (stable by sample index). meta[0..8] = group offsets.
// ---------------------------------------------------------------------------
__global__ __launch_bounds__(256) void bucket_kernel(
    const int* __restrict__ gid, int* __restrict__ meta,
    int* __restrict__ perm) {
  __shared__ unsigned short lc[256][G_];  // per-thread per-group counts
  __shared__ int offs_s[G_ + 1];
  int t = threadIdx.x;
#pragma unroll
  for (int g = 0; g < G_; g++) lc[t][g] = 0;
  int myg[16];
  const int base = t * 16;
#pragma unroll
  for (int j = 0; j < 16; j++) {
    myg[j] = gid[base + j];
    lc[t][myg[j]]++;
  }
  __syncthreads();
  if (t < G_) {
    // serial exclusive prefix over threads for group t
    int run = 0;
    for (int tt = 0; tt < 256; tt++) {
      int v = lc[tt][t];
      lc[tt][t] = (unsigned short)run;
      run += v;
    }
    offs_s[t + 1] = run;  // raw count of group t (prefixed below)
  }
  __syncthreads();
  if (t == 0) {
    int o = 0;
    for (int g = 0; g < G_; g++) {
      int c = offs_s[g + 1];  // read count BEFORE overwriting with prefix
      offs_s[g] = o;
      meta[g] = o;
      o += c;
    }
    offs_s[G_] = o;
    meta[G_] = o;
  }
  __syncthreads();
  int cur[G_];
#pragma unroll
  for (int g = 0; g < G_; g++) cur[g] = offs_s[g] + (int)lc[t][g];
#pragma unroll
  for (int j = 0; j < 16; j++) {
    int g = myg[j];
    perm[cur[g]++] = base + j;
  }
}

// ---------------------------------------------------------------------------
// gemm1: hb[start+r][:] = relu(x[perm]·W1t[g] + b1[g]), bf16, permuted rows.
// 64x64 tile, BK=64, 8 iters, 4 waves (2x2 of 32x32), 16x16x32 bf16 MFMA.
// grid = MAXT*16; mt=b>>4 (row tile), nt=b&15 (H column tile).
// LDS chunk-XOR: 16B chunk c of row r stored at slot c^(r&7). Plain loads +
// plain LDS stores only.
// ---------------------------------------------------------------------------
__global__ __launch_bounds__(256) void gemm1_kernel(
    const float* __restrict__ x, const unsigned short* __restrict__ W1t,
    const float* __restrict__ b1, const int* __restrict__ meta,
    const int* __restrict__ perm, unsigned short* __restrict__ hb) {
  int b = blockIdx.x;
  int mt = b >> 4, nt = b & 15;
  int g, row0, start, cnt;
  if (!tile_lookup(meta, mt, g, row0, start, cnt)) return;
  int n0 = nt * 64;

  __shared__ __attribute__((aligned(16))) unsigned short As[64 * 64];
  __shared__ __attribute__((aligned(16))) unsigned short Bs[64 * 64];
  __shared__ int rows[64];

  int tid = threadIdx.x;
  int lane = tid & 63;
  int wv = tid >> 6;

  if (tid < 64) rows[tid] = perm[start + min(row0 + tid, cnt - 1)];
  __syncthreads();

  // A staging: 4 threads/row, 16 f32 each -> 2 swizzled b128 LDS writes
  int r = tid >> 2, c4 = tid & 3;
  const float* xsrc = x + (size_t)rows[r] * IN_ + c4 * 16;
  unsigned short* adst0 = &As[r * 64 + (((2 * c4) ^ (r & 7)) << 3)];
  unsigned short* adst1 = &As[r * 64 + (((2 * c4 + 1) ^ (r & 7)) << 3)];

  // B staging: lane l of wave wv covers rows wv*16+(l>>3) and +8; source
  // chunk (l&7)^(row&7); LDS dest = lane-ordered base + lane*8 shorts.
  int brow0 = wv * 16 + (lane >> 3);
  int brow1 = brow0 + 8;
  int bsl = lane & 7;
  const unsigned short* bsrc0 = W1t + ((size_t)g * H_ + n0 + brow0) * IN_ +
                                ((bsl ^ (brow0 & 7)) << 3);
  const unsigned short* bsrc1 = W1t + ((size_t)g * H_ + n0 + brow1) * IN_ +
                                ((bsl ^ (brow1 & 7)) << 3);
  unsigned short* bdst0 = &Bs[wv * 1024 + lane * 8];
  unsigned short* bdst1 = &Bs[wv * 1024 + 512 + lane * 8];

  // fragments
  int fl = lane & 15, q = lane >> 4;
  int m0 = (wv >> 1) * 32, nw = (wv & 1) * 32;
  const unsigned short* apA = &As[(m0 + fl) * 64];
  const unsigned short* apB = &As[(m0 + 16 + fl) * 64];
  const unsigned short* bpA = &Bs[(nw + fl) * 64];
  const unsigned short* bpB = &Bs[(nw + 16 + fl) * 64];

  f32x4 acc[2][2];
#pragma unroll
  for (int i = 0; i < 2; i++)
#pragma unroll
    for (int j = 0; j < 2; j++) acc[i][j] = f32x4{0.f, 0.f, 0.f, 0.f};

  float4 v0 = *(const float4*)(xsrc + 0);
  float4 v1 = *(const float4*)(xsrc + 4);
  float4 v2 = *(const float4*)(xsrc + 8);
  float4 v3 = *(const float4*)(xsrc + 12);

  for (int it = 0; it < 8; it++) {
    int k0 = it * 64;
    u16x8 p0 = pack8(v0, v1);
    u16x8 p1 = pack8(v2, v3);
    u16x8 bw0 = *(const u16x8*)(bsrc0 + k0);
    u16x8 bw1 = *(const u16x8*)(bsrc1 + k0);
    __syncthreads();  // prior iteration's consumers done
    *(u16x8*)adst0 = p0;
    *(u16x8*)adst1 = p1;
    *(u16x8*)bdst0 = bw0;
    *(u16x8*)bdst1 = bw1;
    __syncthreads();  // staging visible
    if (it < 7) {     // prefetch next tiles during MFMA phase
      int kn = k0 + 64;
      v0 = *(const float4*)(xsrc + kn);
      v1 = *(const float4*)(xsrc + kn + 4);
      v2 = *(const float4*)(xsrc + kn + 8);
      v3 = *(const float4*)(xsrc + kn + 12);
    }
#pragma unroll
    for (int s = 0; s < 2; s++) {
      int off = (((s << 2) + q) ^ (fl & 7)) << 3;
      bf16x8 a0 = *(const bf16x8*)(apA + off);
      bf16x8 a1 = *(const bf16x8*)(apB + off);
      bf16x8 fb0 = *(const bf16x8*)(bpA + off);
      bf16x8 fb1 = *(const bf16x8*)(bpB + off);
      acc[0][0] = __builtin_amdgcn_mfma_f32_16x16x32_bf16(a0, fb0, acc[0][0], 0, 0, 0);
      acc[1][0] = __builtin_amdgcn_mfma_f32_16x16x32_bf16(a1, fb0, acc[1][0], 0, 0, 0);
      acc[0][1] = __builtin_amdgcn_mfma_f32_16x16x32_bf16(a0, fb1, acc[0][1], 0, 0, 0);
      acc[1][1] = __builtin_amdgcn_mfma_f32_16x16x32_bf16(a1, fb1, acc[1][1], 0, 0, 0);
    }
  }

#pragma unroll
  for (int ni = 0; ni < 2; ni++) {
    int col = n0 + nw + ni * 16 + fl;
    float bias = b1[g * H_ + col];
#pragma unroll
    for (int mi = 0; mi < 2; mi++) {
#pragma unroll
      for (int rg = 0; rg < 4; rg++) {
        int rl = m0 + mi * 16 + q * 4 + rg;
        if (row0 + rl < cnt) {
          float v = fmaxf(acc[mi][ni][rg] + bias, 0.f);
          hb[(size_t)(start + row0 + rl) * H_ + col] = f2bf(v);
        }
      }
    }
  }
}

// ---------------------------------------------------------------------------
// gemm2: y[perm[r]] = hb[r]·W2[g] + b2[g]. Full K=1024 per block (8 iters of
// BK=128), PLAIN stores — no atomics, no memset, deterministic.
// grid = MAXT blocks of 256 threads.
// ---------------------------------------------------------------------------
__global__ __launch_bounds__(256) void gemm2_kernel(
    const unsigned short* __restrict__ hb, const float* __restrict__ W2,
    const float* __restrict__ b2, const int* __restrict__ meta,
    const int* __restrict__ perm, float* __restrict__ y) {
  int mt = blockIdx.x;
  int g, row0, start, cnt;
  if (!tile_lookup(meta, mt, g, row0, start, cnt)) return;

  __shared__ __attribute__((aligned(16))) unsigned short As2[64 * 128];
  __shared__ __attribute__((aligned(16))) unsigned short Bs2[64 * 128];
  __shared__ int rows[64];

  int tid = threadIdx.x;
  int lane = tid & 63;
  int wv = tid >> 6;

  if (tid < 64) rows[tid] = perm[start + min(row0 + tid, cnt - 1)];

  // A staging indices: op j covers 4 rows x 256B; lane l -> row
  // wv*16+j*4+(l>>4), slot l&15, source chunk (l&15)^(row&7).
  int arow_in_op = lane >> 4;
  int asl = lane & 15;
  int arow[4];
  const unsigned short* asrc[4];
#pragma unroll
  for (int j = 0; j < 4; j++) {
    arow[j] = wv * 16 + j * 4 + arow_in_op;
    int cs = asl ^ (arow[j] & 7);
    asrc[j] = hb + (size_t)(start + min(row0 + arow[j], cnt - 1)) * H_ +
              (cs << 3);
  }

  // B staging: thread t covers W2 row k=t>>1, 32 n's
  int kk = tid >> 1;
  int nh = (tid & 1) * 32;
  int kc8 = kk >> 3, kw = kk & 7;

  int fl = lane & 15, q = lane >> 4;
  int m0 = (wv >> 1) * 32, nw = (wv & 1) * 32;
  const unsigned short* apA = &As2[(m0 + fl) * 128];
  const unsigned short* apB = &As2[(m0 + 16 + fl) * 128];
  const unsigned short* bpA = &Bs2[(nw + fl) * 128];
  const unsigned short* bpB = &Bs2[(nw + 16 + fl) * 128];

  f32x4 acc[2][2];
#pragma unroll
  for (int i = 0; i < 2; i++)
#pragma unroll
    for (int j = 0; j < 2; j++) acc[i][j] = f32x4{0.f, 0.f, 0.f, 0.f};

  for (int it = 0; it < 8; it++) {
    int kbase = it * 128;
    // load A chunks to regs
    u16x8 av[4];
#pragma unroll
    for (int j = 0; j < 4; j++) av[j] = *(const u16x8*)(asrc[j] + kbase);
    // load + convert B slice
    const float* wsrc = W2 + ((size_t)g * H_ + kbase + kk) * OUT_ + nh;
    unsigned short bv[32];
#pragma unroll
    for (int i = 0; i < 4; i++) {
      float4 wa = *(const float4*)(wsrc + i * 8);
      float4 wb = *(const float4*)(wsrc + i * 8 + 4);
      bv[i * 8 + 0] = f2bf(wa.x);
      bv[i * 8 + 1] = f2bf(wa.y);
      bv[i * 8 + 2] = f2bf(wa.z);
      bv[i * 8 + 3] = f2bf(wa.w);
      bv[i * 8 + 4] = f2bf(wb.x);
      bv[i * 8 + 5] = f2bf(wb.y);
      bv[i * 8 + 6] = f2bf(wb.z);
      bv[i * 8 + 7] = f2bf(wb.w);
    }
    __syncthreads();  // prior iteration's consumers done
#pragma unroll
    for (int j = 0; j < 4; j++)
      *(u16x8*)&As2[(wv * 16 + j * 4) * 128 + lane * 8] = av[j];
#pragma unroll
    for (int i = 0; i < 32; i++) {
      int n = nh + i;
      Bs2[n * 128 + ((kc8 ^ (n & 7)) << 3) + kw] = bv[i];
    }
    __syncthreads();  // staging visible
#pragma unroll
    for (int s = 0; s < 4; s++) {
      int off = (((s << 2) + q) ^ (fl & 7)) << 3;
      bf16x8 a0 = *(const bf16x8*)(apA + off);
      bf16x8 a1 = *(const bf16x8*)(apB + off);
      bf16x8 fb0 = *(const bf16x8*)(bpA + off);
      bf16x8 fb1 = *(const bf16x8*)(bpB + off);
      acc[0][0] = __builtin_amdgcn_mfma_f32_16x16x32_bf16(a0, fb0, acc[0][0], 0, 0, 0);
      acc[1][0] = __builtin_amdgcn_mfma_f32_16x16x32_bf16(a1, fb0, acc[1][0], 0, 0, 0);
      acc[0][1] = __builtin_amdgcn_mfma_f32_16x16x32_bf16(a0, fb1, acc[0][1], 0, 0, 0);
      acc[1][1] = __builtin_amdgcn_mfma_f32_16x16x32_bf16(a1, fb1, acc[1][1], 0, 0, 0);
    }
  }

#pragma unroll
  for (int ni = 0; ni < 2; ni++) {
    int col = nw + ni * 16 + fl;
    float bias = b2[g * OUT_ + col];
#pragma unroll
    for (int mi = 0; mi < 2; mi++) {
#pragma unroll
      for (int rg = 0; rg < 4; rg++) {
        int rl = m0 + mi * 16 + q * 4 + rg;
        if (row0 + rl < cnt) {
          y[(size_t)rows[rl] * OUT_ + col] = acc[mi][ni][rg] + bias;
        }
      }
    }
  }
}

extern "C" void kernel_launch(void* const* d_in, const int* in_sizes, int n_in,
                              void* d_out, int out_size, void* d_ws,
                              size_t ws_size, hipStream_t stream) {
  const float* x = (const float*)d_in[0];
  const int* gid = (const int*)d_in[1];
  const float* W1 = (const float*)d_in[2];
  const float* b1 = (const float*)d_in[3];
  const float* W2 = (const float*)d_in[4];
  const float* b2 = (const float*)d_in[5];
  float* y = (float*)d_out;

  // ws layout: exactly the round-2-proven 16,793,664 B footprint
  int* meta = (int*)d_ws;                                         // @0 (64 B)
  int* perm = (int*)((char*)d_ws + 64);                           // 16 KB
  unsigned short* W1t = (unsigned short*)((char*)d_ws + 16448);   // 8 MB
  unsigned short* hb = (unsigned short*)((char*)d_ws + 8405056);  // 8 MB

  transpose_w1_kernel<<<4096, 256, 0, stream>>>(W1, W1t);
  bucket_kernel<<<1, 256, 0, stream>>>(gid, meta, perm);
  gemm1_kernel<<<MAXT * 16, 256, 0, stream>>>(x, W1t, b1, meta, perm, hb);
  gemm2_kernel<<<MAXT, 256, 0, stream>>>(hb, W2, b2, meta, perm, y);
}

// Round 6
// 114.396 us; speedup vs baseline: 2.0429x; 1.1235x over previous
//
#include <hip/hip_runtime.h>
#include <hip/hip_bf16.h>

#define B_ 4096
#define G_ 8
#define IN_ 512
#define H_ 1024
#define OUT_ 64
#define MAXT 72  // max 64-row tiles across groups: 64 + 8

typedef float f32x4 __attribute__((ext_vector_type(4)));
typedef __bf16 bf16x8 __attribute__((ext_vector_type(8)));
typedef unsigned short u16x8 __attribute__((ext_vector_type(8)));

__device__ inline unsigned short f2bf(float f) {
  unsigned int u = __builtin_bit_cast(unsigned int, f);
  u += 0x7fffu + ((u >> 16) & 1u);
  return (unsigned short)(u >> 16);
}

__device__ inline u16x8 pack8(float4 a, float4 b) {
  return u16x8{f2bf(a.x), f2bf(a.y), f2bf(a.z), f2bf(a.w),
               f2bf(b.x), f2bf(b.y), f2bf(b.z), f2bf(b.w)};
}

// Tile-table scan: given meta (offs[0..8]) and linear tile id mt, find the
// group g, row0, start, cnt. Returns false if mt >= total tiles.
__device__ inline bool tile_lookup(const int* __restrict__ meta, int mt,
                                   int& g, int& row0, int& start, int& cnt) {
  int ts = 0;
  bool found = false;
#pragma unroll
  for (int gg = 0; gg < G_; gg++) {
    int s = meta[gg], e = meta[gg + 1];
    int T = (e - s + 63) >> 6;
    if (!found && mt >= ts && mt < ts + T) {
      g = gg;
      row0 = (mt - ts) << 6;
      start = s;
      cnt = e - s;
      found = true;
    }
    ts += T;
  }
  return found;
}

// ---------------------------------------------------------------------------
// prep (fused, all blocks independent elementwise/transpose):
//   b in [0,4096):      W1 [G][IN][H] f32 -> W1t [G][H][IN] bf16
//   b in [4096,4608):   W2 [G][H][OUT] f32 -> W2t [G][OUT][H] bf16
//   b in [4608,5632):   x [B][IN] f32 -> xb [B][IN] bf16 (2048 elems/block)
// ---------------------------------------------------------------------------
__global__ __launch_bounds__(256) void prep_kernel(
    const float* __restrict__ W1, const float* __restrict__ W2,
    const float* __restrict__ x, unsigned short* __restrict__ W1t,
    unsigned short* __restrict__ W2t, unsigned short* __restrict__ xb) {
  int b = blockIdx.x;
  int t = threadIdx.x;
  if (b < 4096) {
    __shared__ float tile[32][33];
    int h32 = b & 31, k32 = (b >> 5) & 15, g = b >> 9;
    int kl = t >> 3, nl = (t & 7) * 4;
    const float* src =
        W1 + ((size_t)g * IN_ + k32 * 32 + kl) * H_ + h32 * 32 + nl;
    float4 v = *(const float4*)src;
    tile[kl][nl + 0] = v.x;
    tile[kl][nl + 1] = v.y;
    tile[kl][nl + 2] = v.z;
    tile[kl][nl + 3] = v.w;
    __syncthreads();
    int nl2 = t >> 3, kl2 = (t & 7) * 4;
    ushort4 o;
    o.x = f2bf(tile[kl2 + 0][nl2]);
    o.y = f2bf(tile[kl2 + 1][nl2]);
    o.z = f2bf(tile[kl2 + 2][nl2]);
    o.w = f2bf(tile[kl2 + 3][nl2]);
    *(ushort4*)(W1t + ((size_t)g * H_ + h32 * 32 + nl2) * IN_ + k32 * 32 +
                kl2) = o;
  } else if (b < 4608) {
    __shared__ float tile2[32][33];
    int bb = b - 4096;
    int g = bb >> 6, k32 = (bb >> 1) & 31, n32 = bb & 1;
    int kl = t >> 3, nl = (t & 7) * 4;
    const float* src =
        W2 + ((size_t)g * H_ + k32 * 32 + kl) * OUT_ + n32 * 32 + nl;
    float4 v = *(const float4*)src;
    tile2[kl][nl + 0] = v.x;
    tile2[kl][nl + 1] = v.y;
    tile2[kl][nl + 2] = v.z;
    tile2[kl][nl + 3] = v.w;
    __syncthreads();
    int nl2 = t >> 3, kl2 = (t & 7) * 4;
    ushort4 o;
    o.x = f2bf(tile2[kl2 + 0][nl2]);
    o.y = f2bf(tile2[kl2 + 1][nl2]);
    o.z = f2bf(tile2[kl2 + 2][nl2]);
    o.w = f2bf(tile2[kl2 + 3][nl2]);
    *(ushort4*)(W2t + ((size_t)g * OUT_ + n32 * 32 + nl2) * H_ + k32 * 32 +
                kl2) = o;
  } else {
    int bb = b - 4608;
    size_t base = (size_t)bb * 2048 + t * 8;
    float4 v0 = *(const float4*)(x + base);
    float4 v1 = *(const float4*)(x + base + 4);
    *(u16x8*)(xb + base) = pack8(v0, v1);
  }
}

// ---------------------------------------------------------------------------
// bucket: DETERMINISTIC stable counting sort (round-5 proven). Single block.
// ---------------------------------------------------------------------------
__global__ __launch_bounds__(256) void bucket_kernel(
    const int* __restrict__ gid, int* __restrict__ meta,
    int* __restrict__ perm) {
  __shared__ unsigned short lc[256][G_];
  __shared__ int offs_s[G_ + 1];
  int t = threadIdx.x;
#pragma unroll
  for (int g = 0; g < G_; g++) lc[t][g] = 0;
  int myg[16];
  const int base = t * 16;
#pragma unroll
  for (int j = 0; j < 16; j++) {
    myg[j] = gid[base + j];
    lc[t][myg[j]]++;
  }
  __syncthreads();
  if (t < G_) {
    int run = 0;
    for (int tt = 0; tt < 256; tt++) {
      int v = lc[tt][t];
      lc[tt][t] = (unsigned short)run;
      run += v;
    }
    offs_s[t + 1] = run;
  }
  __syncthreads();
  if (t == 0) {
    int o = 0;
    for (int g = 0; g < G_; g++) {
      int c = offs_s[g + 1];
      offs_s[g] = o;
      meta[g] = o;
      o += c;
    }
    offs_s[G_] = o;
    meta[G_] = o;
  }
  __syncthreads();
  int cur[G_];
#pragma unroll
  for (int g = 0; g < G_; g++) cur[g] = offs_s[g] + (int)lc[t][g];
#pragma unroll
  for (int j = 0; j < 16; j++) {
    int g = myg[j];
    perm[cur[g]++] = base + j;
  }
}

// ---------------------------------------------------------------------------
// gemm1: hb[start+r][:] = relu(xb[perm]·W1t[g] + b1[g]), bf16, permuted rows.
// 64x64 tile, BK=64, 8 iters, 4 waves (2x2 of 32x32), 16x16x32 bf16 MFMA.
// All staging is pure b128 bf16 load->LDS store (conversions hoisted to prep).
// LDS chunk-XOR: 16B chunk c of row r stored at slot c^(r&7).
// ---------------------------------------------------------------------------
__global__ __launch_bounds__(256) void gemm1_kernel(
    const unsigned short* __restrict__ xb, const unsigned short* __restrict__ W1t,
    const float* __restrict__ b1, const int* __restrict__ meta,
    const int* __restrict__ perm, unsigned short* __restrict__ hb) {
  int b = blockIdx.x;
  int mt = b >> 4, nt = b & 15;
  int g, row0, start, cnt;
  if (!tile_lookup(meta, mt, g, row0, start, cnt)) return;
  int n0 = nt * 64;

  __shared__ __attribute__((aligned(16))) unsigned short As[64 * 64];
  __shared__ __attribute__((aligned(16))) unsigned short Bs[64 * 64];
  __shared__ int rows[64];

  int tid = threadIdx.x;
  int lane = tid & 63;
  int wv = tid >> 6;

  if (tid < 64) rows[tid] = perm[start + min(row0 + tid, cnt - 1)];
  __syncthreads();

  // A staging: thread t -> row r=t>>2, chunk pair 2c,2c+1 (c=t&3); 32 B
  // contiguous from xb; swizzled LDS dests.
  int r = tid >> 2, c4 = tid & 3;
  const unsigned short* xsrc = xb + (size_t)rows[r] * IN_ + c4 * 16;
  unsigned short* adst0 = &As[r * 64 + (((2 * c4) ^ (r & 7)) << 3)];
  unsigned short* adst1 = &As[r * 64 + (((2 * c4 + 1) ^ (r & 7)) << 3)];

  // B staging: lane l of wave wv covers rows wv*16+(l>>3) and +8; source
  // chunk (l&7)^(row&7); LDS dest = lane-ordered base + lane*8 shorts.
  int brow0 = wv * 16 + (lane >> 3);
  int brow1 = brow0 + 8;
  int bsl = lane & 7;
  const unsigned short* bsrc0 = W1t + ((size_t)g * H_ + n0 + brow0) * IN_ +
                                ((bsl ^ (brow0 & 7)) << 3);
  const unsigned short* bsrc1 = W1t + ((size_t)g * H_ + n0 + brow1) * IN_ +
                                ((bsl ^ (brow1 & 7)) << 3);
  unsigned short* bdst0 = &Bs[wv * 1024 + lane * 8];
  unsigned short* bdst1 = &Bs[wv * 1024 + 512 + lane * 8];

  // fragments
  int fl = lane & 15, q = lane >> 4;
  int m0 = (wv >> 1) * 32, nw = (wv & 1) * 32;
  const unsigned short* apA = &As[(m0 + fl) * 64];
  const unsigned short* apB = &As[(m0 + 16 + fl) * 64];
  const unsigned short* bpA = &Bs[(nw + fl) * 64];
  const unsigned short* bpB = &Bs[(nw + 16 + fl) * 64];

  f32x4 acc[2][2];
#pragma unroll
  for (int i = 0; i < 2; i++)
#pragma unroll
    for (int j = 0; j < 2; j++) acc[i][j] = f32x4{0.f, 0.f, 0.f, 0.f};

  u16x8 av0 = *(const u16x8*)(xsrc + 0);
  u16x8 av1 = *(const u16x8*)(xsrc + 8);

  for (int it = 0; it < 8; it++) {
    int k0 = it * 64;
    u16x8 bw0 = *(const u16x8*)(bsrc0 + k0);
    u16x8 bw1 = *(const u16x8*)(bsrc1 + k0);
    __syncthreads();  // prior iteration's consumers done
    *(u16x8*)adst0 = av0;
    *(u16x8*)adst1 = av1;
    *(u16x8*)bdst0 = bw0;
    *(u16x8*)bdst1 = bw1;
    __syncthreads();  // staging visible
    if (it < 7) {     // prefetch next A tile during MFMA phase
      int kn = k0 + 64;
      av0 = *(const u16x8*)(xsrc + kn);
      av1 = *(const u16x8*)(xsrc + kn + 8);
    }
#pragma unroll
    for (int s = 0; s < 2; s++) {
      int off = (((s << 2) + q) ^ (fl & 7)) << 3;
      bf16x8 a0 = *(const bf16x8*)(apA + off);
      bf16x8 a1 = *(const bf16x8*)(apB + off);
      bf16x8 fb0 = *(const bf16x8*)(bpA + off);
      bf16x8 fb1 = *(const bf16x8*)(bpB + off);
      acc[0][0] = __builtin_amdgcn_mfma_f32_16x16x32_bf16(a0, fb0, acc[0][0], 0, 0, 0);
      acc[1][0] = __builtin_amdgcn_mfma_f32_16x16x32_bf16(a1, fb0, acc[1][0], 0, 0, 0);
      acc[0][1] = __builtin_amdgcn_mfma_f32_16x16x32_bf16(a0, fb1, acc[0][1], 0, 0, 0);
      acc[1][1] = __builtin_amdgcn_mfma_f32_16x16x32_bf16(a1, fb1, acc[1][1], 0, 0, 0);
    }
  }

#pragma unroll
  for (int ni = 0; ni < 2; ni++) {
    int col = n0 + nw + ni * 16 + fl;
    float bias = b1[g * H_ + col];
#pragma unroll
    for (int mi = 0; mi < 2; mi++) {
#pragma unroll
      for (int rg = 0; rg < 4; rg++) {
        int rl = m0 + mi * 16 + q * 4 + rg;
        if (row0 + rl < cnt) {
          float v = fmaxf(acc[mi][ni][rg] + bias, 0.f);
          hb[(size_t)(start + row0 + rl) * H_ + col] = f2bf(v);
        }
      }
    }
  }
}

// ---------------------------------------------------------------------------
// gemm2: y[perm[r]] = hb[r]·W2t[g] + b2[g]. Full K=1024 per block (8 iters of
// BK=128), plain stores, deterministic. B staging now vectorized bf16 from
// W2t [G][OUT][H]. grid = MAXT blocks of 256 threads.
// ---------------------------------------------------------------------------
__global__ __launch_bounds__(256) void gemm2_kernel(
    const unsigned short* __restrict__ hb, const unsigned short* __restrict__ W2t,
    const float* __restrict__ b2, const int* __restrict__ meta,
    const int* __restrict__ perm, float* __restrict__ y) {
  int mt = blockIdx.x;
  int g, row0, start, cnt;
  if (!tile_lookup(meta, mt, g, row0, start, cnt)) return;

  __shared__ __attribute__((aligned(16))) unsigned short As2[64 * 128];
  __shared__ __attribute__((aligned(16))) unsigned short Bs2[64 * 128];
  __shared__ int rows[64];

  int tid = threadIdx.x;
  int lane = tid & 63;
  int wv = tid >> 6;

  if (tid < 64) rows[tid] = perm[start + min(row0 + tid, cnt - 1)];

  // A staging: op j covers 4 rows x 256B; lane l -> row wv*16+j*4+(l>>4),
  // slot l&15, source chunk (l&15)^(row&7).
  int arow_in_op = lane >> 4;
  int asl = lane & 15;
  const unsigned short* asrc[4];
#pragma unroll
  for (int j = 0; j < 4; j++) {
    int row = wv * 16 + j * 4 + arow_in_op;
    int cs = asl ^ (row & 7);
    asrc[j] = hb + (size_t)(start + min(row0 + row, cnt - 1)) * H_ +
              (cs << 3);
  }

  // B staging: thread t -> row n=t>>2 (0..63), quarter qd=t&3 covering
  // chunks 4qd..4qd+3 (64 B contiguous in W2t row); swizzled LDS dests.
  int bn = tid >> 2, qd = tid & 3;
  const unsigned short* bsrc = W2t + ((size_t)g * OUT_ + bn) * H_ + qd * 32;
  unsigned short* bdst[4];
#pragma unroll
  for (int j = 0; j < 4; j++) {
    int ch = 4 * qd + j;
    bdst[j] = &Bs2[bn * 128 + (((ch ^ (bn & 7)) & 15) << 3)];
  }

  int fl = lane & 15, q = lane >> 4;
  int m0 = (wv >> 1) * 32, nw = (wv & 1) * 32;
  const unsigned short* apA = &As2[(m0 + fl) * 128];
  const unsigned short* apB = &As2[(m0 + 16 + fl) * 128];
  const unsigned short* bpA = &Bs2[(nw + fl) * 128];
  const unsigned short* bpB = &Bs2[(nw + 16 + fl) * 128];

  f32x4 acc[2][2];
#pragma unroll
  for (int i = 0; i < 2; i++)
#pragma unroll
    for (int j = 0; j < 2; j++) acc[i][j] = f32x4{0.f, 0.f, 0.f, 0.f};

  for (int it = 0; it < 8; it++) {
    int kbase = it * 128;
    u16x8 av[4];
#pragma unroll
    for (int j = 0; j < 4; j++) av[j] = *(const u16x8*)(asrc[j] + kbase);
    u16x8 bv[4];
#pragma unroll
    for (int j = 0; j < 4; j++) bv[j] = *(const u16x8*)(bsrc + kbase + j * 8);
    __syncthreads();  // prior iteration's consumers done
#pragma unroll
    for (int j = 0; j < 4; j++)
      *(u16x8*)&As2[(wv * 16 + j * 4) * 128 + lane * 8] = av[j];
#pragma unroll
    for (int j = 0; j < 4; j++) *(u16x8*)bdst[j] = bv[j];
    __syncthreads();  // staging visible
#pragma unroll
    for (int s = 0; s < 4; s++) {
      int off = (((s << 2) + q) ^ (fl & 7)) << 3;
      bf16x8 a0 = *(const bf16x8*)(apA + off);
      bf16x8 a1 = *(const bf16x8*)(apB + off);
      bf16x8 fb0 = *(const bf16x8*)(bpA + off);
      bf16x8 fb1 = *(const bf16x8*)(bpB + off);
      acc[0][0] = __builtin_amdgcn_mfma_f32_16x16x32_bf16(a0, fb0, acc[0][0], 0, 0, 0);
      acc[1][0] = __builtin_amdgcn_mfma_f32_16x16x32_bf16(a1, fb0, acc[1][0], 0, 0, 0);
      acc[0][1] = __builtin_amdgcn_mfma_f32_16x16x32_bf16(a0, fb1, acc[0][1], 0, 0, 0);
      acc[1][1] = __builtin_amdgcn_mfma_f32_16x16x32_bf16(a1, fb1, acc[1][1], 0, 0, 0);
    }
  }

#pragma unroll
  for (int ni = 0; ni < 2; ni++) {
    int col = nw + ni * 16 + fl;
    float bias = b2[g * OUT_ + col];
#pragma unroll
    for (int mi = 0; mi < 2; mi++) {
#pragma unroll
      for (int rg = 0; rg < 4; rg++) {
        int rl = m0 + mi * 16 + q * 4 + rg;
        if (row0 + rl < cnt) {
          y[(size_t)rows[rl] * OUT_ + col] = acc[mi][ni][rg] + bias;
        }
      }
    }
  }
}

extern "C" void kernel_launch(void* const* d_in, const int* in_sizes, int n_in,
                              void* d_out, int out_size, void* d_ws,
                              size_t ws_size, hipStream_t stream) {
  const float* x = (const float*)d_in[0];
  const int* gid = (const int*)d_in[1];
  const float* W1 = (const float*)d_in[2];
  const float* b1 = (const float*)d_in[3];
  const float* W2 = (const float*)d_in[4];
  const float* b2 = (const float*)d_in[5];
  float* y = (float*)d_out;

  // ws layout (d_ws is 256 MiB per harness fill counters; we use ~41 MB)
  int* meta = (int*)d_ws;                                             // 64 B
  int* perm = (int*)((char*)d_ws + 64);                               // 16 KB
  unsigned short* W1t = (unsigned short*)((char*)d_ws + (1u << 16));  // 8 MB
  unsigned short* W2t = (unsigned short*)((char*)d_ws + (16u << 20)); // 1 MB
  unsigned short* xb = (unsigned short*)((char*)d_ws + (24u << 20));  // 4 MB
  unsigned short* hb = (unsigned short*)((char*)d_ws + (32u << 20));  // 8 MB

  prep_kernel<<<5632, 256, 0, stream>>>(W1, W2, x, W1t, W2t, xb);
  bucket_kernel<<<1, 256, 0, stream>>>(gid, meta, perm);
  gemm1_kernel<<<MAXT * 16, 256, 0, stream>>>(xb, W1t, b1, meta, perm, hb);
  gemm2_kernel<<<MAXT, 256, 0, stream>>>(hb, W2t, b2, meta, perm, y);
}

// Round 7
// 108.956 us; speedup vs baseline: 2.1449x; 1.0499x over previous
//
#include <hip/hip_runtime.h>
#include <hip/hip_bf16.h>

#define B_ 4096
#define G_ 8
#define IN_ 512
#define H_ 1024
#define OUT_ 64
#define MAXT 72  // max 64-row tiles across groups: 64 + 8

typedef float f32x4 __attribute__((ext_vector_type(4)));
typedef __bf16 bf16x8 __attribute__((ext_vector_type(8)));
typedef unsigned short u16x8 __attribute__((ext_vector_type(8)));

__device__ inline unsigned short f2bf(float f) {
  unsigned int u = __builtin_bit_cast(unsigned int, f);
  u += 0x7fffu + ((u >> 16) & 1u);
  return (unsigned short)(u >> 16);
}

__device__ inline u16x8 pack8(float4 a, float4 b) {
  return u16x8{f2bf(a.x), f2bf(a.y), f2bf(a.z), f2bf(a.w),
               f2bf(b.x), f2bf(b.y), f2bf(b.z), f2bf(b.w)};
}

// Tile-table scan: given meta (offs[0..8]) and linear tile id mt, find the
// group g, row0, start, cnt. Returns false if mt >= total tiles.
__device__ inline bool tile_lookup(const int* __restrict__ meta, int mt,
                                   int& g, int& row0, int& start, int& cnt) {
  int ts = 0;
  bool found = false;
#pragma unroll
  for (int gg = 0; gg < G_; gg++) {
    int s = meta[gg], e = meta[gg + 1];
    int T = (e - s + 63) >> 6;
    if (!found && mt >= ts && mt < ts + T) {
      g = gg;
      row0 = (mt - ts) << 6;
      start = s;
      cnt = e - s;
      found = true;
    }
    ts += T;
  }
  return found;
}

// ---------------------------------------------------------------------------
// prep (fused, all blocks independent):
//   b in [0,4096):      W1 [G][IN][H] f32 -> W1t [G][H][IN] bf16
//   b in [4096,4608):   W2 [G][H][OUT] f32 -> W2t [G][OUT][H] bf16
//   b in [4608,5632):   x [B][IN] f32 -> xb bf16 (2048 elems/block)
//   b == 5632:          deterministic stable bucket (no atomics):
//                       meta[0..8]=offs, perm = stable counting sort of gid
// ---------------------------------------------------------------------------
__global__ __launch_bounds__(256) void prep_kernel(
    const float* __restrict__ W1, const float* __restrict__ W2,
    const float* __restrict__ x, const int* __restrict__ gid,
    unsigned short* __restrict__ W1t, unsigned short* __restrict__ W2t,
    unsigned short* __restrict__ xb, int* __restrict__ meta,
    int* __restrict__ perm) {
  int b = blockIdx.x;
  int t = threadIdx.x;
  if (b < 4096) {
    __shared__ float tile[32][33];
    int h32 = b & 31, k32 = (b >> 5) & 15, g = b >> 9;
    int kl = t >> 3, nl = (t & 7) * 4;
    const float* src =
        W1 + ((size_t)g * IN_ + k32 * 32 + kl) * H_ + h32 * 32 + nl;
    float4 v = *(const float4*)src;
    tile[kl][nl + 0] = v.x;
    tile[kl][nl + 1] = v.y;
    tile[kl][nl + 2] = v.z;
    tile[kl][nl + 3] = v.w;
    __syncthreads();
    int nl2 = t >> 3, kl2 = (t & 7) * 4;
    ushort4 o;
    o.x = f2bf(tile[kl2 + 0][nl2]);
    o.y = f2bf(tile[kl2 + 1][nl2]);
    o.z = f2bf(tile[kl2 + 2][nl2]);
    o.w = f2bf(tile[kl2 + 3][nl2]);
    *(ushort4*)(W1t + ((size_t)g * H_ + h32 * 32 + nl2) * IN_ + k32 * 32 +
                kl2) = o;
  } else if (b < 4608) {
    __shared__ float tile2[32][33];
    int bb = b - 4096;
    int g = bb >> 6, k32 = (bb >> 1) & 31, n32 = bb & 1;
    int kl = t >> 3, nl = (t & 7) * 4;
    const float* src =
        W2 + ((size_t)g * H_ + k32 * 32 + kl) * OUT_ + n32 * 32 + nl;
    float4 v = *(const float4*)src;
    tile2[kl][nl + 0] = v.x;
    tile2[kl][nl + 1] = v.y;
    tile2[kl][nl + 2] = v.z;
    tile2[kl][nl + 3] = v.w;
    __syncthreads();
    int nl2 = t >> 3, kl2 = (t & 7) * 4;
    ushort4 o;
    o.x = f2bf(tile2[kl2 + 0][nl2]);
    o.y = f2bf(tile2[kl2 + 1][nl2]);
    o.z = f2bf(tile2[kl2 + 2][nl2]);
    o.w = f2bf(tile2[kl2 + 3][nl2]);
    *(ushort4*)(W2t + ((size_t)g * OUT_ + n32 * 32 + nl2) * H_ + k32 * 32 +
                kl2) = o;
  } else if (b < 5632) {
    int bb = b - 4608;
    size_t base = (size_t)bb * 2048 + t * 8;
    float4 v0 = *(const float4*)(x + base);
    float4 v1 = *(const float4*)(x + base + 4);
    *(u16x8*)(xb + base) = pack8(v0, v1);
  } else {
    // bucket: transposed count matrix + per-group 32-lane segmented scan
    __shared__ unsigned short lc[G_][256];
    __shared__ int offs_s[G_ + 1];
#pragma unroll
    for (int g = 0; g < G_; g++) lc[g][t] = 0;
    int myg[16];
    const int base = t * 16;
#pragma unroll
    for (int j = 0; j < 16; j++) {
      myg[j] = gid[base + j];
      lc[myg[j]][t]++;  // own column: race-free; u16 halves byte-enabled
    }
    __syncthreads();
    // group g = t>>5 scanned by 32 lanes k = t&31; entries lc[g][8k..8k+7]
    {
      int g = t >> 5, k = t & 31;
      unsigned short pref[8];
      int s = 0;
#pragma unroll
      for (int j = 0; j < 8; j++) {
        pref[j] = (unsigned short)s;
        s += lc[g][8 * k + j];
      }
      int incl = s;
#pragma unroll
      for (int d = 1; d < 32; d <<= 1) {
        int o = __shfl_up(incl, d, 32);
        if (k >= d) incl += o;
      }
      int excl = incl - s;
      if (k == 31) offs_s[g + 1] = incl;  // raw group total (prefixed below)
#pragma unroll
      for (int j = 0; j < 8; j++)
        lc[g][8 * k + j] = (unsigned short)(excl + pref[j]);
    }
    __syncthreads();
    if (t == 0) {
      int o = 0;
      for (int g = 0; g < G_; g++) {
        int c = offs_s[g + 1];
        offs_s[g] = o;
        meta[g] = o;
        o += c;
      }
      offs_s[G_] = o;
      meta[G_] = o;
    }
    __syncthreads();
    int cur[G_];
#pragma unroll
    for (int g = 0; g < G_; g++) cur[g] = offs_s[g] + (int)lc[g][t];
#pragma unroll
    for (int j = 0; j < 16; j++) {
      int g = myg[j];
      perm[cur[g]++] = base + j;
    }
  }
}

// ---------------------------------------------------------------------------
// gemm1: hb[start+r][:] = relu(xb[perm]·W1t[g] + b1[g]), bf16, permuted rows.
// 64x64 tile, BK=64, 8 iters, 4 waves (2x2 of 32x32), 16x16x32 bf16 MFMA.
// PIPELINED: double-buffered LDS, ONE barrier/iter, global loads issued one
// iteration ahead (reg-landed loads stay in flight across s_barrier).
// LDS chunk-XOR: 16B chunk c of row r stored at slot c^(r&7).
// ---------------------------------------------------------------------------
__global__ __launch_bounds__(256) void gemm1_kernel(
    const unsigned short* __restrict__ xb,
    const unsigned short* __restrict__ W1t, const float* __restrict__ b1,
    const int* __restrict__ meta, const int* __restrict__ perm,
    unsigned short* __restrict__ hb) {
  int b = blockIdx.x;
  int mt = b >> 4, nt = b & 15;
  int g, row0, start, cnt;
  if (!tile_lookup(meta, mt, g, row0, start, cnt)) return;
  int n0 = nt * 64;

  __shared__ __attribute__((aligned(16))) unsigned short As[2][64 * 64];
  __shared__ __attribute__((aligned(16))) unsigned short Bs[2][64 * 64];
  __shared__ int rows[64];

  int tid = threadIdx.x;
  int lane = tid & 63;
  int wv = tid >> 6;

  if (tid < 64) rows[tid] = perm[start + min(row0 + tid, cnt - 1)];
  __syncthreads();

  // A staging: thread t -> row r=t>>2, chunk pair 2c,2c+1 (c=t&3)
  int r = tid >> 2, c4 = tid & 3;
  const unsigned short* xsrc = xb + (size_t)rows[r] * IN_ + c4 * 16;
  int aoff0 = r * 64 + (((2 * c4) ^ (r & 7)) << 3);
  int aoff1 = r * 64 + (((2 * c4 + 1) ^ (r & 7)) << 3);

  // B staging: lane l of wave wv covers rows wv*16+(l>>3) and +8; source
  // chunk (l&7)^(row&7); LDS dest = lane-ordered base + lane*8 shorts.
  int brow0 = wv * 16 + (lane >> 3);
  int brow1 = brow0 + 8;
  int bsl = lane & 7;
  const unsigned short* bsrc0 = W1t + ((size_t)g * H_ + n0 + brow0) * IN_ +
                                ((bsl ^ (brow0 & 7)) << 3);
  const unsigned short* bsrc1 = W1t + ((size_t)g * H_ + n0 + brow1) * IN_ +
                                ((bsl ^ (brow1 & 7)) << 3);
  int boff0 = wv * 1024 + lane * 8;
  int boff1 = wv * 1024 + 512 + lane * 8;

  // fragment offsets (within one 64x64 tile)
  int fl = lane & 15, q = lane >> 4;
  int m0 = (wv >> 1) * 32, nw = (wv & 1) * 32;
  int apA = (m0 + fl) * 64;
  int apB = (m0 + 16 + fl) * 64;
  int bpA = (nw + fl) * 64;
  int bpB = (nw + 16 + fl) * 64;

  f32x4 acc[2][2];
#pragma unroll
  for (int i = 0; i < 2; i++)
#pragma unroll
    for (int j = 0; j < 2; j++) acc[i][j] = f32x4{0.f, 0.f, 0.f, 0.f};

  // prologue: L0 -> buf0; issue L1
  u16x8 av0 = *(const u16x8*)(xsrc + 0);
  u16x8 av1 = *(const u16x8*)(xsrc + 8);
  u16x8 bw0 = *(const u16x8*)(bsrc0 + 0);
  u16x8 bw1 = *(const u16x8*)(bsrc1 + 0);
  *(u16x8*)&As[0][aoff0] = av0;
  *(u16x8*)&As[0][aoff1] = av1;
  *(u16x8*)&Bs[0][boff0] = bw0;
  *(u16x8*)&Bs[0][boff1] = bw1;
  av0 = *(const u16x8*)(xsrc + 64);
  av1 = *(const u16x8*)(xsrc + 64 + 8);
  bw0 = *(const u16x8*)(bsrc0 + 64);
  bw1 = *(const u16x8*)(bsrc1 + 64);
  __syncthreads();  // buf0 visible; L1 loads remain in flight

  for (int it = 0; it < 8; it++) {
    int p = it & 1;
    if (it < 7) {  // commit L_{it+1} regs to the other buffer
      *(u16x8*)&As[p ^ 1][aoff0] = av0;
      *(u16x8*)&As[p ^ 1][aoff1] = av1;
      *(u16x8*)&Bs[p ^ 1][boff0] = bw0;
      *(u16x8*)&Bs[p ^ 1][boff1] = bw1;
    }
    if (it < 6) {  // issue L_{it+2}, in flight for a full iteration
      int kn = (it + 2) * 64;
      av0 = *(const u16x8*)(xsrc + kn);
      av1 = *(const u16x8*)(xsrc + kn + 8);
      bw0 = *(const u16x8*)(bsrc0 + kn);
      bw1 = *(const u16x8*)(bsrc1 + kn);
    }
#pragma unroll
    for (int s = 0; s < 2; s++) {
      int off = (((s << 2) + q) ^ (fl & 7)) << 3;
      bf16x8 a0 = *(const bf16x8*)&As[p][apA + off];
      bf16x8 a1 = *(const bf16x8*)&As[p][apB + off];
      bf16x8 fb0 = *(const bf16x8*)&Bs[p][bpA + off];
      bf16x8 fb1 = *(const bf16x8*)&Bs[p][bpB + off];
      acc[0][0] = __builtin_amdgcn_mfma_f32_16x16x32_bf16(a0, fb0, acc[0][0], 0, 0, 0);
      acc[1][0] = __builtin_amdgcn_mfma_f32_16x16x32_bf16(a1, fb0, acc[1][0], 0, 0, 0);
      acc[0][1] = __builtin_amdgcn_mfma_f32_16x16x32_bf16(a0, fb1, acc[0][1], 0, 0, 0);
      acc[1][1] = __builtin_amdgcn_mfma_f32_16x16x32_bf16(a1, fb1, acc[1][1], 0, 0, 0);
    }
    __syncthreads();  // one barrier/iter: p^1 writes visible, p reads done
  }

#pragma unroll
  for (int ni = 0; ni < 2; ni++) {
    int col = n0 + nw + ni * 16 + fl;
    float bias = b1[g * H_ + col];
#pragma unroll
    for (int mi = 0; mi < 2; mi++) {
#pragma unroll
      for (int rg = 0; rg < 4; rg++) {
        int rl = m0 + mi * 16 + q * 4 + rg;
        if (row0 + rl < cnt) {
          float v = fmaxf(acc[mi][ni][rg] + bias, 0.f);
          hb[(size_t)(start + row0 + rl) * H_ + col] = f2bf(v);
        }
      }
    }
  }
}

// ---------------------------------------------------------------------------
// gemm2: y[perm[r]] = hb[r]·W2t[g] + b2[g]. Full K=1024 (8 iters of BK=128),
// plain stores, deterministic. PIPELINED like gemm1: double LDS buffer, one
// barrier/iter, loads issued one iteration ahead.
// ---------------------------------------------------------------------------
__global__ __launch_bounds__(256) void gemm2_kernel(
    const unsigned short* __restrict__ hb,
    const unsigned short* __restrict__ W2t, const float* __restrict__ b2,
    const int* __restrict__ meta, const int* __restrict__ perm,
    float* __restrict__ y) {
  int mt = blockIdx.x;
  int g, row0, start, cnt;
  if (!tile_lookup(meta, mt, g, row0, start, cnt)) return;

  __shared__ __attribute__((aligned(16))) unsigned short As2[2][64 * 128];
  __shared__ __attribute__((aligned(16))) unsigned short Bs2[2][64 * 128];
  __shared__ int rows[64];

  int tid = threadIdx.x;
  int lane = tid & 63;
  int wv = tid >> 6;

  if (tid < 64) rows[tid] = perm[start + min(row0 + tid, cnt - 1)];

  // A staging: op j covers 4 rows x 256B; lane l -> row wv*16+j*4+(l>>4),
  // slot l&15, source chunk (l&15)^(row&7).
  int arow_in_op = lane >> 4;
  int asl = lane & 15;
  const unsigned short* asrc[4];
  int adst[4];
#pragma unroll
  for (int j = 0; j < 4; j++) {
    int row = wv * 16 + j * 4 + arow_in_op;
    int cs = asl ^ (row & 7);
    asrc[j] =
        hb + (size_t)(start + min(row0 + row, cnt - 1)) * H_ + (cs << 3);
    adst[j] = (wv * 16 + j * 4) * 128 + lane * 8;
  }

  // B staging: thread t -> row n=t>>2, quarter qd=t&3 (chunks 4qd..4qd+3)
  int bn = tid >> 2, qd = tid & 3;
  const unsigned short* bsrc = W2t + ((size_t)g * OUT_ + bn) * H_ + qd * 32;
  int bdst[4];
#pragma unroll
  for (int j = 0; j < 4; j++) {
    int ch = 4 * qd + j;
    bdst[j] = bn * 128 + ((ch ^ (bn & 7)) << 3);
  }

  int fl = lane & 15, q = lane >> 4;
  int m0 = (wv >> 1) * 32, nw = (wv & 1) * 32;
  int apA = (m0 + fl) * 128;
  int apB = (m0 + 16 + fl) * 128;
  int bpA = (nw + fl) * 128;
  int bpB = (nw + 16 + fl) * 128;

  f32x4 acc[2][2];
#pragma unroll
  for (int i = 0; i < 2; i++)
#pragma unroll
    for (int j = 0; j < 2; j++) acc[i][j] = f32x4{0.f, 0.f, 0.f, 0.f};

  // prologue: L0 -> buf0; issue L1
  u16x8 av[4], bv[4];
#pragma unroll
  for (int j = 0; j < 4; j++) av[j] = *(const u16x8*)(asrc[j] + 0);
#pragma unroll
  for (int j = 0; j < 4; j++) bv[j] = *(const u16x8*)(bsrc + j * 8);
#pragma unroll
  for (int j = 0; j < 4; j++) *(u16x8*)&As2[0][adst[j]] = av[j];
#pragma unroll
  for (int j = 0; j < 4; j++) *(u16x8*)&Bs2[0][bdst[j]] = bv[j];
#pragma unroll
  for (int j = 0; j < 4; j++) av[j] = *(const u16x8*)(asrc[j] + 128);
#pragma unroll
  for (int j = 0; j < 4; j++) bv[j] = *(const u16x8*)(bsrc + 128 + j * 8);
  __syncthreads();  // buf0 visible; L1 in flight

  for (int it = 0; it < 8; it++) {
    int p = it & 1;
    if (it < 7) {
#pragma unroll
      for (int j = 0; j < 4; j++) *(u16x8*)&As2[p ^ 1][adst[j]] = av[j];
#pragma unroll
      for (int j = 0; j < 4; j++) *(u16x8*)&Bs2[p ^ 1][bdst[j]] = bv[j];
    }
    if (it < 6) {
      int kn = (it + 2) * 128;
#pragma unroll
      for (int j = 0; j < 4; j++) av[j] = *(const u16x8*)(asrc[j] + kn);
#pragma unroll
      for (int j = 0; j < 4; j++)
        bv[j] = *(const u16x8*)(bsrc + kn + j * 8);
    }
#pragma unroll
    for (int s = 0; s < 4; s++) {
      int off = (((s << 2) + q) ^ (fl & 7)) << 3;
      bf16x8 a0 = *(const bf16x8*)&As2[p][apA + off];
      bf16x8 a1 = *(const bf16x8*)&As2[p][apB + off];
      bf16x8 fb0 = *(const bf16x8*)&Bs2[p][bpA + off];
      bf16x8 fb1 = *(const bf16x8*)&Bs2[p][bpB + off];
      acc[0][0] = __builtin_amdgcn_mfma_f32_16x16x32_bf16(a0, fb0, acc[0][0], 0, 0, 0);
      acc[1][0] = __builtin_amdgcn_mfma_f32_16x16x32_bf16(a1, fb0, acc[1][0], 0, 0, 0);
      acc[0][1] = __builtin_amdgcn_mfma_f32_16x16x32_bf16(a0, fb1, acc[0][1], 0, 0, 0);
      acc[1][1] = __builtin_amdgcn_mfma_f32_16x16x32_bf16(a1, fb1, acc[1][1], 0, 0, 0);
    }
    __syncthreads();
  }

#pragma unroll
  for (int ni = 0; ni < 2; ni++) {
    int col = nw + ni * 16 + fl;
    float bias = b2[g * OUT_ + col];
#pragma unroll
    for (int mi = 0; mi < 2; mi++) {
#pragma unroll
      for (int rg = 0; rg < 4; rg++) {
        int rl = m0 + mi * 16 + q * 4 + rg;
        if (row0 + rl < cnt) {
          y[(size_t)rows[rl] * OUT_ + col] = acc[mi][ni][rg] + bias;
        }
      }
    }
  }
}

extern "C" void kernel_launch(void* const* d_in, const int* in_sizes, int n_in,
                              void* d_out, int out_size, void* d_ws,
                              size_t ws_size, hipStream_t stream) {
  const float* x = (const float*)d_in[0];
  const int* gid = (const int*)d_in[1];
  const float* W1 = (const float*)d_in[2];
  const float* b1 = (const float*)d_in[3];
  const float* W2 = (const float*)d_in[4];
  const float* b2 = (const float*)d_in[5];
  float* y = (float*)d_out;

  // ws layout (~41 MB used of the available workspace)
  int* meta = (int*)d_ws;                                             // 64 B
  int* perm = (int*)((char*)d_ws + 64);                               // 16 KB
  unsigned short* W1t = (unsigned short*)((char*)d_ws + (1u << 16));  // 8 MB
  unsigned short* W2t = (unsigned short*)((char*)d_ws + (16u << 20)); // 1 MB
  unsigned short* xb = (unsigned short*)((char*)d_ws + (24u << 20));  // 4 MB
  unsigned short* hb = (unsigned short*)((char*)d_ws + (32u << 20));  // 8 MB

  prep_kernel<<<5633, 256, 0, stream>>>(W1, W2, x, gid, W1t, W2t, xb, meta,
                                        perm);
  gemm1_kernel<<<MAXT * 16, 256, 0, stream>>>(xb, W1t, b1, meta, perm, hb);
  gemm2_kernel<<<MAXT, 256, 0, stream>>>(hb, W2t, b2, meta, perm, y);
}